// Round 1
// baseline (77.575 us; speedup 1.0000x reference)
//
#include <hip/hip_runtime.h>

// Embedding row gather: out[b*t][64] = weight[x[b*t]][64]
// x: int32 [4096*200], weight: float32 [1,000,000 x 64], out: float32 [819200 x 64]
// One float4 per thread; 16 threads per row (64 floats = 16 x float4 = 256 B).

__global__ __launch_bounds__(256) void emb_gather_kernel(
    const int* __restrict__ x,
    const float* __restrict__ w,
    float* __restrict__ out,
    long long n_rows)
{
    long long gid = (long long)blockIdx.x * blockDim.x + threadIdx.x;
    long long total = n_rows * 16;  // 16 float4 chunks per row
    if (gid >= total) return;

    long long row = gid >> 4;       // which bag/row
    int sub = (int)(gid & 15);      // which float4 within the row

    long long idx = (long long)x[row];  // gather index into weight table

    const float4* __restrict__ src = reinterpret_cast<const float4*>(w + idx * 64);
    float4* __restrict__ dst = reinterpret_cast<float4*>(out + row * 64);
    dst[sub] = src[sub];
}

extern "C" void kernel_launch(void* const* d_in, const int* in_sizes, int n_in,
                              void* d_out, int out_size, void* d_ws, size_t ws_size,
                              hipStream_t stream) {
    const int*   x = (const int*)d_in[0];      // [4096*200] int32
    const float* w = (const float*)d_in[1];    // [1e6 * 64] float32
    float*       out = (float*)d_out;          // [819200 * 64] float32

    long long n_rows = (long long)in_sizes[0]; // 819200
    long long total_threads = n_rows * 16;

    int block = 256;
    long long grid = (total_threads + block - 1) / block;

    emb_gather_kernel<<<(unsigned)grid, block, 0, stream>>>(x, w, out, n_rows);
}

// Round 3
// 64.538 us; speedup vs baseline: 1.2020x; 1.2020x over previous
//
#include <hip/hip_runtime.h>

// Embedding row gather: out[b*t][64] = weight[x[b*t]][64]
// x: int32 [4096*200], weight: float32 [1,000,000 x 64], out: float32 [819200 x 64]
// One 16B vector per thread; 16 threads per row (64 floats = 16 x 16B = 256 B).
// Output stores are non-temporal: the 210 MB streaming write must not evict
// the 256 MB weight table from L2/L3 (table reuse factor ~1.46x).

typedef float vfloat4 __attribute__((ext_vector_type(4)));

__global__ __launch_bounds__(256) void emb_gather_kernel(
    const int* __restrict__ x,
    const float* __restrict__ w,
    float* __restrict__ out,
    long long n_rows)
{
    long long gid = (long long)blockIdx.x * blockDim.x + threadIdx.x;
    long long total = n_rows * 16;  // 16 16B chunks per row
    if (gid >= total) return;

    long long row = gid >> 4;       // which bag/row
    int sub = (int)(gid & 15);      // which 16B chunk within the row

    long long idx = (long long)x[row];  // gather index into weight table

    const vfloat4* __restrict__ src = reinterpret_cast<const vfloat4*>(w + idx * 64);
    vfloat4 v = src[sub];

    vfloat4* dst = reinterpret_cast<vfloat4*>(out + row * 64) + sub;
    __builtin_nontemporal_store(v, dst);
}

extern "C" void kernel_launch(void* const* d_in, const int* in_sizes, int n_in,
                              void* d_out, int out_size, void* d_ws, size_t ws_size,
                              hipStream_t stream) {
    const int*   x = (const int*)d_in[0];      // [4096*200] int32
    const float* w = (const float*)d_in[1];    // [1e6 * 64] float32
    float*       out = (float*)d_out;          // [819200 * 64] float32

    long long n_rows = (long long)in_sizes[0]; // 819200
    long long total_threads = n_rows * 16;

    int block = 256;
    long long grid = (total_threads + block - 1) / block;

    emb_gather_kernel<<<(unsigned)grid, block, 0, stream>>>(x, w, out, n_rows);
}